// Round 2
// baseline (9882.181 us; speedup 1.0000x reference)
//
#include <hip/hip_runtime.h>
#include <hip/hip_bf16.h>

#define N_EVENT 10000
#define N_IOC   40000
#define N_NODES 50000
#define E_EDGES 800000
#define D_EV 768
#define D_IO 128
#define H 256
#define R 8
#define NBASES 8
#define NLAYERS 3
#define EDIM 16
#define LN_EPS 1e-5f
#define TM 64

// Block-wide LayerNorm stats over H=256 values (one per thread).
__device__ __forceinline__ void block_ln(float v, float& mu, float& var) {
    float s = v, s2 = v * v;
    #pragma unroll
    for (int o = 32; o > 0; o >>= 1) {
        s  += __shfl_xor(s, o);
        s2 += __shfl_xor(s2, o);
    }
    __shared__ float red[8];
    int w = threadIdx.x >> 6;
    if ((threadIdx.x & 63) == 0) { red[w] = s; red[4 + w] = s2; }
    __syncthreads();
    s  = red[0] + red[1] + red[2] + red[3];
    s2 = red[4] + red[5] + red[6] + red[7];
    mu  = s * (1.0f / H);
    var = s2 * (1.0f / H) - mu * mu;
}

// ---- input projection: h[n] = relu(LN(x[n] @ W + b)) ----
__global__ __launch_bounds__(256) void proj_kernel(
    const float* __restrict__ xev, const float* __restrict__ xio,
    const float* __restrict__ wev, const float* __restrict__ bev,
    const float* __restrict__ gev, const float* __restrict__ betev,
    const float* __restrict__ wio, const float* __restrict__ bio,
    const float* __restrict__ gio, const float* __restrict__ betio,
    float* __restrict__ h)
{
    int n = blockIdx.x;
    int j = threadIdx.x;
    __shared__ float xs[D_EV];
    const float *x, *w, *bb, *g, *be;
    int D;
    if (n < N_EVENT) { x = xev + (size_t)n * D_EV; w = wev; bb = bev; g = gev; be = betev; D = D_EV; }
    else             { x = xio + (size_t)(n - N_EVENT) * D_IO; w = wio; bb = bio; g = gio; be = betio; D = D_IO; }
    for (int k = j; k < D; k += 256) xs[k] = x[k];
    __syncthreads();
    float acc = bb[j];
    for (int k = 0; k < D; ++k) acc += xs[k] * w[(size_t)k * H + j];
    float mu, var;
    block_ln(acc, mu, var);
    float y = (acc - mu) * rsqrtf(var + LN_EPS) * g[j] + be[j];
    h[(size_t)n * H + j] = fmaxf(y, 0.0f);
}

// ---- edge MLP lookup table: ctab[r] = emb[r] @ W[:16] + b ; wlast = W[16] ----
__global__ __launch_bounds__(256) void edge_table_kernel(
    const float* __restrict__ emb, const float* __restrict__ mlp_w,
    const float* __restrict__ mlp_b, float* __restrict__ ctab, float* __restrict__ wlast)
{
    int r = blockIdx.x, j = threadIdx.x;
    float acc = mlp_b[j];
    #pragma unroll
    for (int k = 0; k < EDIM; ++k) acc += emb[r * EDIM + k] * mlp_w[k * H + j];
    ctab[r * H + j] = acc;
    if (r == 0) wlast[j] = mlp_w[EDIM * H + j];
}

// ---- edge feature scatter + degree / per-(dst,rel) counts ----
__global__ __launch_bounds__(256) void scatter_enh_kernel(
    const int* __restrict__ ei, const int* __restrict__ et, const float* __restrict__ ew,
    const float* __restrict__ ctab, const float* __restrict__ wlast,
    float* __restrict__ enh_sum, float* __restrict__ deg, float* __restrict__ cnt)
{
    int j = threadIdx.x;
    long e0 = (long)blockIdx.x * 4;
    for (int i = 0; i < 4; ++i) {
        long e = e0 + i;
        if (e >= E_EDGES) return;
        int t = et[e];
        int d = ei[E_EDGES + e];
        float wgt = ew[e];
        float v = fmaxf(ctab[t * H + j] + wgt * wlast[j], 0.0f);
        atomicAdd(&enh_sum[(size_t)d * H + j], v);
        if (j == 0) {
            atomicAdd(&deg[d], 1.0f);
            atomicAdd(&cnt[d * R + t], 1.0f);
        }
    }
}

__global__ __launch_bounds__(256) void enh_final_kernel(float* __restrict__ enh, const float* __restrict__ deg)
{
    int n = blockIdx.x, j = threadIdx.x;
    enh[(size_t)n * H + j] *= (1.0f / fmaxf(deg[n], 1.0f));
}

__global__ __launch_bounds__(256) void cinv_kernel(float* __restrict__ cnt)
{
    int i = blockIdx.x * 256 + threadIdx.x;
    if (i < N_NODES * R) cnt[i] = 1.0f / fmaxf(cnt[i], 1.0f);
}

// ---- per-layer relation weights: Bmat[0:2048] = basis-combined w[r], Bmat[2048:2304] = root ----
__global__ __launch_bounds__(256) void build_B_kernel(
    const float* __restrict__ bases, const float* __restrict__ comp, const float* __restrict__ root,
    float* __restrict__ Bmat, int l)
{
    int row = blockIdx.x;
    int j = threadIdx.x;
    float v;
    if (row < R * H) {
        int r = row >> 8, kk = row & 255;
        v = 0.0f;
        const float* bs = bases + (size_t)l * NBASES * H * H + (size_t)kk * H + j;
        const float* cp = comp + (l * R + r) * NBASES;
        #pragma unroll
        for (int b = 0; b < NBASES; ++b) v += cp[b] * bs[(size_t)b * H * H];
    } else {
        int kk = row - R * H;
        v = root[((size_t)l * H + kk) * H + j];
    }
    Bmat[(size_t)row * H + j] = v;
}

// ---- scatter edges of relation r: pre_r[dst] += h[src] * cinv[dst,r] ----
__global__ __launch_bounds__(256) void scatter_msg_kernel(
    const int* __restrict__ ei, const int* __restrict__ et,
    const float* __restrict__ h, const float* __restrict__ cinv,
    float* __restrict__ pre, int r)
{
    int j = threadIdx.x;
    long e0 = (long)blockIdx.x * 16;
    long e1 = e0 + 16; if (e1 > E_EDGES) e1 = E_EDGES;
    for (long e = e0; e < e1; ++e) {
        if (et[e] != r) continue;
        int s = ei[e], d = ei[E_EDGES + e];
        float v = h[(size_t)s * H + j] * cinv[d * R + r];
        atomicAdd(&pre[(size_t)d * H + j], v);
    }
}

// ---- tiled fp32 GEMM: agg (+)= A0 @ B0 [+ A1 @ B1], each K=256, A strides = 256 ----
__global__ __launch_bounds__(256) void gemm_kernel(
    const float* __restrict__ A0, const float* __restrict__ B0,
    const float* __restrict__ A1, const float* __restrict__ B1,
    float* __restrict__ agg, int nseg, int accum)
{
    int j = threadIdx.x;
    int n0 = blockIdx.x * TM;
    __shared__ float As[TM][16];
    __shared__ float Bs[16][H];
    float acc[TM];
    #pragma unroll
    for (int r = 0; r < TM; ++r) acc[r] = 0.0f;

    for (int seg = 0; seg < nseg; ++seg) {
        const float* A = seg ? A1 : A0;
        const float* B = seg ? B1 : B0;
        for (int k0 = 0; k0 < H; k0 += 16) {
            // stage B chunk [16 x 256]
            const float4* Bv = (const float4*)(B + (size_t)k0 * H);
            float4* Bsv = (float4*)&Bs[0][0];
            #pragma unroll
            for (int t = 0; t < 4; ++t) Bsv[j + t * 256] = Bv[j + t * 256];
            // stage A chunk [64 x 16]
            {
                int row = j >> 2, c4 = j & 3;
                int n = n0 + row; if (n >= N_NODES) n = N_NODES - 1;
                *(float4*)&As[row][c4 * 4] = *(const float4*)(A + (size_t)n * H + k0 + c4 * 4);
            }
            __syncthreads();
            float breg[16];
            #pragma unroll
            for (int kk = 0; kk < 16; ++kk) breg[kk] = Bs[kk][j];
            #pragma unroll
            for (int row = 0; row < TM; ++row) {
                const float4* av = (const float4*)&As[row][0];
                float4 a0 = av[0], a1 = av[1], a2 = av[2], a3 = av[3];
                float s0 = a0.x * breg[0] + a0.y * breg[1] + a0.z * breg[2] + a0.w * breg[3];
                float s1 = a1.x * breg[4] + a1.y * breg[5] + a1.z * breg[6] + a1.w * breg[7];
                float s2 = a2.x * breg[8] + a2.y * breg[9] + a2.z * breg[10] + a2.w * breg[11];
                float s3 = a3.x * breg[12] + a3.y * breg[13] + a3.z * breg[14] + a3.w * breg[15];
                acc[row] += (s0 + s1) + (s2 + s3);
            }
            __syncthreads();
        }
    }
    #pragma unroll
    for (int row = 0; row < TM; ++row) {
        int n = n0 + row;
        if (n < N_NODES) {
            size_t idx = (size_t)n * H + j;
            agg[idx] = accum ? (agg[idx] + acc[row]) : acc[row];
        }
    }
}

// ---- layer epilogue: h = h + relu(LN(agg + bias + 0.1*enh_mean)) ----
__global__ __launch_bounds__(256) void finalize_kernel(
    const float* __restrict__ agg, const float* __restrict__ enh,
    const float* __restrict__ bias, const float* __restrict__ gamma, const float* __restrict__ beta,
    float* __restrict__ h, int l)
{
    int n = blockIdx.x, j = threadIdx.x;
    size_t idx = (size_t)n * H + j;
    float v = agg[idx] + bias[l * H + j] + 0.1f * enh[idx];
    float mu, var;
    block_ln(v, mu, var);
    float y = (v - mu) * rsqrtf(var + LN_EPS) * gamma[l * H + j] + beta[l * H + j];
    h[idx] += fmaxf(y, 0.0f);
}

__global__ __launch_bounds__(256) void out_kernel(const float* __restrict__ h, float* __restrict__ out)
{
    size_t i = (size_t)blockIdx.x * 256 + threadIdx.x;
    if (i < (size_t)N_EVENT * H) out[i] = h[i];
}

extern "C" void kernel_launch(void* const* d_in, const int* in_sizes, int n_in,
                              void* d_out, int out_size, void* d_ws, size_t ws_size,
                              hipStream_t stream)
{
    const float* xev   = (const float*)d_in[0];
    const float* xio   = (const float*)d_in[1];
    const int*   ei    = (const int*)d_in[2];
    const int*   et    = (const int*)d_in[3];
    const float* ew    = (const float*)d_in[4];
    const float* wev   = (const float*)d_in[5];
    const float* bev   = (const float*)d_in[6];
    const float* gev   = (const float*)d_in[7];
    const float* betev = (const float*)d_in[8];
    const float* wio   = (const float*)d_in[9];
    const float* bio   = (const float*)d_in[10];
    const float* gio   = (const float*)d_in[11];
    const float* betio = (const float*)d_in[12];
    const float* emb   = (const float*)d_in[13];
    const float* mlp_w = (const float*)d_in[14];
    const float* mlp_b = (const float*)d_in[15];
    const float* bases = (const float*)d_in[16];
    const float* comp  = (const float*)d_in[17];
    const float* root  = (const float*)d_in[18];
    const float* bias  = (const float*)d_in[19];
    const float* gamma = (const float*)d_in[20];
    const float* beta  = (const float*)d_in[21];

    float* ws = (float*)d_ws;
    size_t o = 0;
    float* h     = ws + o; o += (size_t)N_NODES * H;   // 12.8M floats
    float* enh   = ws + o; o += (size_t)N_NODES * H;   // 12.8M
    float* agg   = ws + o; o += (size_t)N_NODES * H;   // 12.8M
    float* pre   = ws + o; o += (size_t)N_NODES * H;   // 12.8M (per-relation bucket)
    float* cnt   = ws + o; o += (size_t)N_NODES * R;   // 0.4M  (becomes cinv)
    float* deg   = ws + o; o += (size_t)N_NODES;       // 50K
    float* Bmat  = ws + o; o += (size_t)(R * H + H) * H; // 589824
    float* ctab  = ws + o; o += R * H;
    float* wlast = ws + o; o += H;
    // total ~209 MB fp32

    hipMemsetAsync(enh, 0, (size_t)N_NODES * H * sizeof(float), stream);
    hipMemsetAsync(cnt, 0, (size_t)N_NODES * R * sizeof(float), stream);
    hipMemsetAsync(deg, 0, (size_t)N_NODES * sizeof(float), stream);

    proj_kernel<<<N_NODES, 256, 0, stream>>>(xev, xio, wev, bev, gev, betev,
                                             wio, bio, gio, betio, h);
    edge_table_kernel<<<R, 256, 0, stream>>>(emb, mlp_w, mlp_b, ctab, wlast);
    scatter_enh_kernel<<<(E_EDGES + 3) / 4, 256, 0, stream>>>(ei, et, ew, ctab, wlast,
                                                              enh, deg, cnt);
    enh_final_kernel<<<N_NODES, 256, 0, stream>>>(enh, deg);
    cinv_kernel<<<(N_NODES * R + 255) / 256, 256, 0, stream>>>(cnt);

    for (int l = 0; l < NLAYERS; ++l) {
        build_B_kernel<<<R * H + H, 256, 0, stream>>>(bases, comp, root, Bmat, l);
        for (int r = 0; r < R; ++r) {
            hipMemsetAsync(pre, 0, (size_t)N_NODES * H * sizeof(float), stream);
            scatter_msg_kernel<<<(E_EDGES + 15) / 16, 256, 0, stream>>>(ei, et, h, cnt, pre, r);
            int nseg = (r == R - 1) ? 2 : 1;
            int accum = (r != 0) ? 1 : 0;
            gemm_kernel<<<(N_NODES + TM - 1) / TM, 256, 0, stream>>>(
                pre, Bmat + (size_t)r * H * H,
                h, Bmat + (size_t)R * H * H,
                agg, nseg, accum);
        }
        finalize_kernel<<<N_NODES, 256, 0, stream>>>(agg, enh, bias, gamma, beta, h, l);
    }

    out_kernel<<<((size_t)N_EVENT * H + 255) / 256, 256, 0, stream>>>(h, (float*)d_out);
}

// Round 3
// 4464.003 us; speedup vs baseline: 2.2137x; 2.2137x over previous
//
#include <hip/hip_runtime.h>
#include <hip/hip_bf16.h>

#define N_EVENT 10000
#define N_IOC   40000
#define N_NODES 50000
#define E_EDGES 800000
#define D_EV 768
#define D_IO 128
#define H 256
#define R 8
#define NBASES 8
#define NLAYERS 3
#define EDIM 16
#define LN_EPS 1e-5f

#define NKEY (N_NODES * R)            // 400000 (dst,rel) buckets
#define SCAN_CHUNK 2048
#define NCHUNK ((NKEY + SCAN_CHUNK - 1) / SCAN_CHUNK)  // 196
#define NC 5000                        // node-chunk for bucket+gemm (ws budget)
#define NCHUNKS (N_NODES / NC)         // 10 (exact)
#define KPRE (R * H)                   // 2048
#define KTOT (R * H + H)               // 2304 (8 relations + root)

typedef __hip_bfloat16 bf16;
typedef __attribute__((ext_vector_type(8))) short bf16x8;
typedef __attribute__((ext_vector_type(4))) float f32x4;

__device__ __forceinline__ float us2f(unsigned short u) {
    union { unsigned int i; float f; } x; x.i = ((unsigned int)u) << 16; return x.f;
}
__device__ __forceinline__ unsigned short f2us(float f) {
    bf16 h = __float2bfloat16(f);
    return *(unsigned short*)&h;
}

// Block-wide LayerNorm stats over H=256 values (one per thread).
__device__ __forceinline__ void block_ln(float v, float& mu, float& var) {
    float s = v, s2 = v * v;
    #pragma unroll
    for (int o = 32; o > 0; o >>= 1) {
        s  += __shfl_xor(s, o);
        s2 += __shfl_xor(s2, o);
    }
    __shared__ float red[8];
    int w = threadIdx.x >> 6;
    if ((threadIdx.x & 63) == 0) { red[w] = s; red[4 + w] = s2; }
    __syncthreads();
    s  = red[0] + red[1] + red[2] + red[3];
    s2 = red[4] + red[5] + red[6] + red[7];
    mu  = s * (1.0f / H);
    var = s2 * (1.0f / H) - mu * mu;
}

// ---- histogram of (dst,rel) keys ----
__global__ __launch_bounds__(256) void hist_kernel(const int* __restrict__ ei, const int* __restrict__ et,
                                                   int* __restrict__ cnt) {
    int e = blockIdx.x * 256 + threadIdx.x;
    if (e < E_EDGES) atomicAdd(&cnt[ei[E_EDGES + e] * R + et[e]], 1);
}

// ---- 3-kernel exclusive scan over NKEY ints ----
__global__ __launch_bounds__(256) void scan1_kernel(const int* __restrict__ cnt, int* __restrict__ offs,
                                                    int* __restrict__ bsum) {
    __shared__ int s[256];
    int t = threadIdx.x;
    long base = (long)blockIdx.x * SCAN_CHUNK + t * 8;
    int v[8]; int sum = 0;
    #pragma unroll
    for (int i = 0; i < 8; ++i) { long idx = base + i; v[i] = (idx < NKEY) ? cnt[idx] : 0; sum += v[i]; }
    s[t] = sum; __syncthreads();
    for (int off = 1; off < 256; off <<= 1) {
        int x = (t >= off) ? s[t - off] : 0;
        __syncthreads();
        s[t] += x;
        __syncthreads();
    }
    int run = s[t] - sum;                 // exclusive within chunk
    if (t == 255) bsum[blockIdx.x] = s[255];
    #pragma unroll
    for (int i = 0; i < 8; ++i) { long idx = base + i; if (idx < NKEY) offs[idx] = run; run += v[i]; }
}

__global__ __launch_bounds__(256) void scan2_kernel(int* __restrict__ bsum) {
    __shared__ int s[256];
    int t = threadIdx.x;
    int v = (t < NCHUNK) ? bsum[t] : 0;
    s[t] = v; __syncthreads();
    for (int off = 1; off < 256; off <<= 1) {
        int x = (t >= off) ? s[t - off] : 0;
        __syncthreads();
        s[t] += x;
        __syncthreads();
    }
    if (t < NCHUNK) bsum[t] = s[t] - v;   // exclusive
}

__global__ __launch_bounds__(256) void scan3_kernel(int* __restrict__ offs, const int* __restrict__ bsum) {
    int i = blockIdx.x * 256 + threadIdx.x;
    if (i < NKEY) offs[i] += bsum[i / SCAN_CHUNK];
    if (i == 0) offs[NKEY] = E_EDGES;
}

__global__ __launch_bounds__(256) void cinv_kernel(const int* __restrict__ cnt, float* __restrict__ cinv) {
    int i = blockIdx.x * 256 + threadIdx.x;
    if (i < NKEY) cinv[i] = 1.0f / (float)max(cnt[i], 1);
}

// ---- counting-sort scatter: sorted by key=dst*R+rel (uses cnt as count-down cursor) ----
__global__ __launch_bounds__(256) void sort_kernel(const int* __restrict__ ei, const int* __restrict__ et,
                                                   const float* __restrict__ ew, const int* __restrict__ offs,
                                                   int* __restrict__ cnt, int* __restrict__ ssrc,
                                                   float* __restrict__ sew) {
    int e = blockIdx.x * 256 + threadIdx.x;
    if (e >= E_EDGES) return;
    int key = ei[E_EDGES + e] * R + et[e];
    int pos = offs[key] + atomicSub(&cnt[key], 1) - 1;
    ssrc[pos] = ei[e];
    sew[pos]  = ew[e];
}

// ---- input projection: h[n] = relu(LN(x[n] @ W + b)); writes fp32 h and bf16 hb ----
__global__ __launch_bounds__(256) void proj_kernel(
    const float* __restrict__ xev, const float* __restrict__ xio,
    const float* __restrict__ wev, const float* __restrict__ bev,
    const float* __restrict__ gev, const float* __restrict__ betev,
    const float* __restrict__ wio, const float* __restrict__ bio,
    const float* __restrict__ gio, const float* __restrict__ betio,
    float* __restrict__ h, bf16* __restrict__ hb)
{
    int n = blockIdx.x;
    int j = threadIdx.x;
    __shared__ float xs[D_EV];
    const float *x, *w, *bb, *g, *be;
    int D;
    if (n < N_EVENT) { x = xev + (size_t)n * D_EV; w = wev; bb = bev; g = gev; be = betev; D = D_EV; }
    else             { x = xio + (size_t)(n - N_EVENT) * D_IO; w = wio; bb = bio; g = gio; be = betio; D = D_IO; }
    for (int k = j; k < D; k += 256) xs[k] = x[k];
    __syncthreads();
    float acc = bb[j];
    for (int k = 0; k < D; ++k) acc += xs[k] * w[(size_t)k * H + j];
    float mu, var;
    block_ln(acc, mu, var);
    float y = fmaxf((acc - mu) * rsqrtf(var + LN_EPS) * g[j] + be[j], 0.0f);
    size_t idx = (size_t)n * H + j;
    h[idx] = y;
    hb[idx] = __float2bfloat16(y);
}

// ---- edge MLP lookup table ----
__global__ __launch_bounds__(256) void edge_table_kernel(
    const float* __restrict__ emb, const float* __restrict__ mlp_w,
    const float* __restrict__ mlp_b, float* __restrict__ ctab, float* __restrict__ wlast)
{
    int r = blockIdx.x, j = threadIdx.x;
    float acc = mlp_b[j];
    #pragma unroll
    for (int k = 0; k < EDIM; ++k) acc += emb[r * EDIM + k] * mlp_w[k * H + j];
    ctab[r * H + j] = acc;
    if (r == 0) wlast[j] = mlp_w[EDIM * H + j];
}

// ---- enh mean via sorted buckets: one wave per dst, no atomics ----
__global__ __launch_bounds__(256) void enh_bucket_kernel(
    const int* __restrict__ offs, const float* __restrict__ sew,
    const float* __restrict__ ctab, const float* __restrict__ wlast,
    bf16* __restrict__ enh)
{
    __shared__ float ct[R * H];
    __shared__ float wl[H];
    for (int i = threadIdx.x; i < R * H; i += 256) ct[i] = ctab[i];
    for (int i = threadIdx.x; i < H; i += 256) wl[i] = wlast[i];
    __syncthreads();
    int w = threadIdx.x >> 6, lane = threadIdx.x & 63;
    int d = blockIdx.x * 4 + w;
    float acc[4] = {0.f, 0.f, 0.f, 0.f};
    int j0 = offs[d * R], jend = offs[d * R + R];
    int deg = jend - j0;
    for (int r = 0; r < R; ++r) {
        int a = offs[d * R + r], b = offs[d * R + r + 1];
        for (int j = a; j < b; ++j) {
            float wt = sew[j];
            #pragma unroll
            for (int i = 0; i < 4; ++i) {
                int c = lane * 4 + i;
                acc[i] += fmaxf(ct[r * H + c] + wt * wl[c], 0.0f);
            }
        }
    }
    float inv = 1.0f / fmaxf((float)deg, 1.0f);
    unsigned short o[4];
    #pragma unroll
    for (int i = 0; i < 4; ++i) o[i] = f2us(acc[i] * inv);
    *(ushort4*)(enh + (size_t)d * H + lane * 4) = *(ushort4*)o;
}

// ---- per-layer stacked Bt: Bt[n][k], k = r*256+i -> W_r[i][n], k = 2048+i -> root[i][n] ----
__global__ __launch_bounds__(256) void build_Bt_kernel(
    const float* __restrict__ bases, const float* __restrict__ comp, const float* __restrict__ root,
    bf16* __restrict__ Bt, int l)
{
    int krow = blockIdx.x;
    int n = threadIdx.x;
    float v;
    if (krow < KPRE) {
        int r = krow >> 8, kk = krow & 255;
        v = 0.0f;
        const float* bs = bases + (size_t)l * NBASES * H * H + (size_t)kk * H + n;
        const float* cp = comp + (l * R + r) * NBASES;
        #pragma unroll
        for (int b = 0; b < NBASES; ++b) v += cp[b] * bs[(size_t)b * H * H];
    } else {
        int kk = krow - KPRE;
        v = root[((size_t)l * H + kk) * H + n];
    }
    Bt[(size_t)n * KTOT + krow] = __float2bfloat16(v);
}

// ---- bucket sums: pre[d][r*256+c] = cinv[d,r] * sum_{e in (d,r)} hb[src][c]; one wave per dst ----
__global__ __launch_bounds__(256) void bucket_msg_kernel(
    const int* __restrict__ offs, const int* __restrict__ ssrc,
    const bf16* __restrict__ hb, const float* __restrict__ cinv,
    bf16* __restrict__ pre, int c0)
{
    int w = threadIdx.x >> 6, lane = threadIdx.x & 63;
    int d = c0 + blockIdx.x * 4 + w;
    size_t prow = (size_t)(d - c0) * KPRE;
    for (int r = 0; r < R; ++r) {
        float acc[4] = {0.f, 0.f, 0.f, 0.f};
        int a = offs[d * R + r], b = offs[d * R + r + 1];
        for (int j = a; j < b; ++j) {
            int s = ssrc[j];
            ushort4 u = *(const ushort4*)(hb + (size_t)s * H + lane * 4);
            acc[0] += us2f(u.x); acc[1] += us2f(u.y); acc[2] += us2f(u.z); acc[3] += us2f(u.w);
        }
        float sc = cinv[d * R + r];
        unsigned short o[4];
        #pragma unroll
        for (int i = 0; i < 4; ++i) o[i] = f2us(acc[i] * sc);
        *(ushort4*)(pre + prow + r * H + lane * 4) = *(ushort4*)o;
    }
}

// ---- MFMA GEMM: agg[c0+n][:] = [pre | hb] row_n (K=2304) @ Bt^T; full K in one pass ----
__global__ __launch_bounds__(256) void gemm_kernel(
    const bf16* __restrict__ pre, const bf16* __restrict__ hb,
    const bf16* __restrict__ Bt, float* __restrict__ agg, int c0)
{
    __shared__ bf16 bts[256 * 40];        // 32-k chunk of Bt, stride 40 (pad) -> <=2-way banks
    int t = threadIdx.x, w = t >> 6, lane = t & 63;
    int quad = lane >> 4, m = lane & 15;
    int rowbase = blockIdx.x * 64 + w * 16;
    f32x4 acc[16];
    #pragma unroll
    for (int c = 0; c < 16; ++c) { acc[c][0] = 0.f; acc[c][1] = 0.f; acc[c][2] = 0.f; acc[c][3] = 0.f; }
    int rowA = rowbase + m;
    int rA = (rowA < NC) ? rowA : (NC - 1);
    const bf16* Apre = pre + (size_t)rA * KPRE;
    const bf16* Ahb  = hb + (size_t)(c0 + rA) * H;

    for (int kc = 0; kc < KTOT / 32; ++kc) {
        int k0 = kc * 32;
        // stage Bt[:, k0..k0+32) -> LDS (thread t = output col n)
        {
            const bf16* g = Bt + (size_t)t * KTOT + k0;
            bf16* l = bts + t * 40;
            *(bf16x8*)(l + 0)  = *(const bf16x8*)(g + 0);
            *(bf16x8*)(l + 8)  = *(const bf16x8*)(g + 8);
            *(bf16x8*)(l + 16) = *(const bf16x8*)(g + 16);
            *(bf16x8*)(l + 24) = *(const bf16x8*)(g + 24);
        }
        // A fragment: lane holds A[row=m][k = quad*8 + 0..7]
        bf16x8 a;
        if (k0 < KPRE) a = *(const bf16x8*)(Apre + k0 + quad * 8);
        else           a = *(const bf16x8*)(Ahb + (k0 - KPRE) + quad * 8);
        __syncthreads();
        #pragma unroll
        for (int c = 0; c < 16; ++c) {
            bf16x8 b = *(const bf16x8*)(bts + (c * 16 + m) * 40 + quad * 8);
            acc[c] = __builtin_amdgcn_mfma_f32_16x16x32_bf16(a, b, acc[c], 0, 0, 0);
        }
        __syncthreads();
    }
    // C/D layout: col = lane&15 (+c*16), row = quad*4 + i
    #pragma unroll
    for (int c = 0; c < 16; ++c) {
        #pragma unroll
        for (int i = 0; i < 4; ++i) {
            int row = rowbase + quad * 4 + i;
            if (row < NC) agg[(size_t)(c0 + row) * H + c * 16 + m] = acc[c][i];
        }
    }
}

// ---- layer epilogue: h += relu(LN(agg + bias + 0.1*enh)); refresh hb ----
__global__ __launch_bounds__(256) void finalize_kernel(
    const float* __restrict__ agg, const bf16* __restrict__ enh,
    const float* __restrict__ bias, const float* __restrict__ gamma, const float* __restrict__ beta,
    float* __restrict__ h, bf16* __restrict__ hb, int l)
{
    int n = blockIdx.x, j = threadIdx.x;
    size_t idx = (size_t)n * H + j;
    float v = agg[idx] + bias[l * H + j] + 0.1f * us2f(*(const unsigned short*)(enh + idx));
    float mu, var;
    block_ln(v, mu, var);
    float y = (v - mu) * rsqrtf(var + LN_EPS) * gamma[l * H + j] + beta[l * H + j];
    float hn = h[idx] + fmaxf(y, 0.0f);
    h[idx] = hn;
    hb[idx] = __float2bfloat16(hn);
}

__global__ __launch_bounds__(256) void out_kernel(const float* __restrict__ h, float* __restrict__ out)
{
    size_t i = (size_t)blockIdx.x * 256 + threadIdx.x;
    if (i < (size_t)N_EVENT * H) out[i] = h[i];
}

extern "C" void kernel_launch(void* const* d_in, const int* in_sizes, int n_in,
                              void* d_out, int out_size, void* d_ws, size_t ws_size,
                              hipStream_t stream)
{
    const float* xev   = (const float*)d_in[0];
    const float* xio   = (const float*)d_in[1];
    const int*   ei    = (const int*)d_in[2];
    const int*   et    = (const int*)d_in[3];
    const float* ew    = (const float*)d_in[4];
    const float* wev   = (const float*)d_in[5];
    const float* bev   = (const float*)d_in[6];
    const float* gev   = (const float*)d_in[7];
    const float* betev = (const float*)d_in[8];
    const float* wio   = (const float*)d_in[9];
    const float* bio   = (const float*)d_in[10];
    const float* gio   = (const float*)d_in[11];
    const float* betio = (const float*)d_in[12];
    const float* emb   = (const float*)d_in[13];
    const float* mlp_w = (const float*)d_in[14];
    const float* mlp_b = (const float*)d_in[15];
    const float* bases = (const float*)d_in[16];
    const float* comp  = (const float*)d_in[17];
    const float* root  = (const float*)d_in[18];
    const float* bias  = (const float*)d_in[19];
    const float* gamma = (const float*)d_in[20];
    const float* beta  = (const float*)d_in[21];

    float* ws = (float*)d_ws;
    size_t o = 0;
    float* h     = ws + o; o += (size_t)N_NODES * H;        // fp32 activations
    float* agg   = ws + o; o += (size_t)N_NODES * H;        // fp32 gemm output
    bf16*  hb    = (bf16*)(ws + o); o += (size_t)N_NODES * H / 2;   // bf16 activations
    bf16*  pre   = (bf16*)(ws + o); o += (size_t)NC * KPRE / 2;     // bf16 bucket sums (chunk)
    bf16*  enh   = (bf16*)(ws + o); o += (size_t)N_NODES * H / 2;   // bf16 edge-feature means
    bf16*  Bt    = (bf16*)(ws + o); o += (size_t)H * KTOT / 2;      // bf16 stacked weights^T
    float* ctab  = ws + o; o += R * H;
    float* wlast = ws + o; o += H;
    float* cinv  = ws + o; o += NKEY;
    int*   bsum  = (int*)(ws + o); o += 256;
    int*   cnt   = (int*)(ws + o); o += NKEY;
    int*   offs  = (int*)(ws + o); o += NKEY + 4;
    int*   ssrc  = (int*)(ws + o); o += E_EDGES;
    float* sew   = ws + o; o += E_EDGES;
    // ~186.5 MB total

    hipMemsetAsync(cnt, 0, (size_t)NKEY * sizeof(int), stream);

    // edge sort by (dst, rel)
    hist_kernel<<<(E_EDGES + 255) / 256, 256, 0, stream>>>(ei, et, cnt);
    scan1_kernel<<<NCHUNK, 256, 0, stream>>>(cnt, offs, bsum);
    scan2_kernel<<<1, 256, 0, stream>>>(bsum);
    scan3_kernel<<<(NKEY + 255) / 256, 256, 0, stream>>>(offs, bsum);
    cinv_kernel<<<(NKEY + 255) / 256, 256, 0, stream>>>(cnt, cinv);
    sort_kernel<<<(E_EDGES + 255) / 256, 256, 0, stream>>>(ei, et, ew, offs, cnt, ssrc, sew);

    // node features + edge-feature means
    proj_kernel<<<N_NODES, 256, 0, stream>>>(xev, xio, wev, bev, gev, betev,
                                             wio, bio, gio, betio, h, hb);
    edge_table_kernel<<<R, 256, 0, stream>>>(emb, mlp_w, mlp_b, ctab, wlast);
    enh_bucket_kernel<<<N_NODES / 4, 256, 0, stream>>>(offs, sew, ctab, wlast, enh);

    for (int l = 0; l < NLAYERS; ++l) {
        build_Bt_kernel<<<KTOT, 256, 0, stream>>>(bases, comp, root, Bt, l);
        for (int c = 0; c < NCHUNKS; ++c) {
            int c0 = c * NC;
            bucket_msg_kernel<<<NC / 4, 256, 0, stream>>>(offs, ssrc, hb, cinv, pre, c0);
            gemm_kernel<<<(NC + 63) / 64, 256, 0, stream>>>(pre, hb, Bt, agg, c0);
        }
        finalize_kernel<<<N_NODES, 256, 0, stream>>>(agg, enh, bias, gamma, beta, h, hb, l);
    }

    out_kernel<<<((size_t)N_EVENT * H + 255) / 256, 256, 0, stream>>>(h, (float*)d_out);
}

// Round 4
// 2274.628 us; speedup vs baseline: 4.3445x; 1.9625x over previous
//
#include <hip/hip_runtime.h>
#include <hip/hip_bf16.h>

#define N_EVENT 10000
#define N_IOC   40000
#define N_NODES 50000
#define E_EDGES 800000
#define D_EV 768
#define D_IO 128
#define H 256
#define R 8
#define NBASES 8
#define NLAYERS 3
#define EDIM 16
#define LN_EPS 1e-5f

#define NKEY (N_NODES * R)
#define SCAN_CHUNK 2048
#define NCHUNK ((NKEY + SCAN_CHUNK - 1) / SCAN_CHUNK)
#define NC 12500                       // node-chunk for bucket+gemm
#define NCHUNKS (N_NODES / NC)         // 4 (exact)
#define KPRE (R * H)                   // 2048
#define KTOT (R * H + H)               // 2304
#define NBLK_EV ((N_EVENT + 63) / 64)  // 157
#define NBLK_IO (N_IOC / 64)           // 625

typedef __hip_bfloat16 bf16;
typedef __attribute__((ext_vector_type(8))) short bf16x8;
typedef __attribute__((ext_vector_type(4))) float f32x4;

__device__ __forceinline__ float us2f(unsigned short u) {
    union { unsigned int i; float f; } x; x.i = ((unsigned int)u) << 16; return x.f;
}

// ===================== edge presort (counting sort by dst*R+rel) =====================
__global__ __launch_bounds__(256) void hist_kernel(const int* __restrict__ ei, const int* __restrict__ et,
                                                   int* __restrict__ cnt) {
    int e = blockIdx.x * 256 + threadIdx.x;
    if (e < E_EDGES) atomicAdd(&cnt[ei[E_EDGES + e] * R + et[e]], 1);
}

__global__ __launch_bounds__(256) void scan1_kernel(const int* __restrict__ cnt, int* __restrict__ offs,
                                                    int* __restrict__ bsum) {
    __shared__ int s[256];
    int t = threadIdx.x;
    long base = (long)blockIdx.x * SCAN_CHUNK + t * 8;
    int v[8]; int sum = 0;
    #pragma unroll
    for (int i = 0; i < 8; ++i) { long idx = base + i; v[i] = (idx < NKEY) ? cnt[idx] : 0; sum += v[i]; }
    s[t] = sum; __syncthreads();
    for (int off = 1; off < 256; off <<= 1) {
        int x = (t >= off) ? s[t - off] : 0;
        __syncthreads();
        s[t] += x;
        __syncthreads();
    }
    int run = s[t] - sum;
    if (t == 255) bsum[blockIdx.x] = s[255];
    #pragma unroll
    for (int i = 0; i < 8; ++i) { long idx = base + i; if (idx < NKEY) offs[idx] = run; run += v[i]; }
}

__global__ __launch_bounds__(256) void scan2_kernel(int* __restrict__ bsum) {
    __shared__ int s[256];
    int t = threadIdx.x;
    int v = (t < NCHUNK) ? bsum[t] : 0;
    s[t] = v; __syncthreads();
    for (int off = 1; off < 256; off <<= 1) {
        int x = (t >= off) ? s[t - off] : 0;
        __syncthreads();
        s[t] += x;
        __syncthreads();
    }
    if (t < NCHUNK) bsum[t] = s[t] - v;
}

__global__ __launch_bounds__(256) void scan3_kernel(int* __restrict__ offs, const int* __restrict__ bsum) {
    int i = blockIdx.x * 256 + threadIdx.x;
    if (i < NKEY) offs[i] += bsum[i / SCAN_CHUNK];
    if (i == 0) offs[NKEY] = E_EDGES;
}

__global__ __launch_bounds__(256) void cinv_kernel(const int* __restrict__ cnt, float* __restrict__ cinv) {
    int i = blockIdx.x * 256 + threadIdx.x;
    if (i < NKEY) cinv[i] = 1.0f / (float)max(cnt[i], 1);
}

__global__ __launch_bounds__(256) void sort_kernel(const int* __restrict__ ei, const int* __restrict__ et,
                                                   const float* __restrict__ ew, const int* __restrict__ offs,
                                                   int* __restrict__ cnt, int* __restrict__ ssrc,
                                                   float* __restrict__ sew) {
    int e = blockIdx.x * 256 + threadIdx.x;
    if (e >= E_EDGES) return;
    int key = ei[E_EDGES + e] * R + et[e];
    int pos = offs[key] + atomicSub(&cnt[key], 1) - 1;
    ssrc[pos] = ei[e];
    sew[pos]  = ew[e];
}

// ===================== dtype prep =====================
__global__ __launch_bounds__(256) void cvt_x_kernel(const float* __restrict__ xev, const float* __restrict__ xio,
                                                    bf16* __restrict__ xevb, bf16* __restrict__ xiob) {
    const long NEV4 = (long)N_EVENT * D_EV / 4;       // 1,920,000
    const long NTOT4 = NEV4 + (long)N_IOC * D_IO / 4; // 3,200,000
    long i = (long)blockIdx.x * 256 + threadIdx.x;
    if (i >= NTOT4) return;
    const float4* src; ushort4* dst; long j;
    if (i < NEV4) { src = (const float4*)xev; dst = (ushort4*)xevb; j = i; }
    else          { src = (const float4*)xio; dst = (ushort4*)xiob; j = i - NEV4; }
    float4 v = src[j];
    ushort4 o;
    bf16 a0 = __float2bfloat16(v.x), a1 = __float2bfloat16(v.y);
    bf16 a2 = __float2bfloat16(v.z), a3 = __float2bfloat16(v.w);
    o.x = *(unsigned short*)&a0; o.y = *(unsigned short*)&a1;
    o.z = *(unsigned short*)&a2; o.w = *(unsigned short*)&a3;
    dst[j] = o;
}

// transpose+convert weights to [n][k] bf16
__global__ __launch_bounds__(256) void cvt_w_kernel(const float* __restrict__ wev, const float* __restrict__ wio,
                                                    bf16* __restrict__ wevT, bf16* __restrict__ wioT) {
    int n = blockIdx.x;
    for (int k = threadIdx.x; k < D_EV; k += 256)
        wevT[(size_t)n * D_EV + k] = __float2bfloat16(wev[(size_t)k * H + n]);
    for (int k = threadIdx.x; k < D_IO; k += 256)
        wioT[(size_t)n * D_IO + k] = __float2bfloat16(wio[(size_t)k * H + n]);
}

// stacked relation weights for all layers, transposed: Bt3[l][n][k]
__global__ __launch_bounds__(256) void build_Bt_kernel(
    const float* __restrict__ bases, const float* __restrict__ comp, const float* __restrict__ root,
    bf16* __restrict__ Bt3) {
    int gb = blockIdx.x;
    int l = gb / KTOT, krow = gb % KTOT;
    int n = threadIdx.x;
    float v;
    if (krow < KPRE) {
        int r = krow >> 8, kk = krow & 255;
        v = 0.0f;
        const float* bs = bases + (size_t)l * NBASES * H * H + (size_t)kk * H + n;
        const float* cp = comp + (l * R + r) * NBASES;
        #pragma unroll
        for (int b = 0; b < NBASES; ++b) v += cp[b] * bs[(size_t)b * H * H];
    } else {
        int kk = krow - KPRE;
        v = root[((size_t)l * H + kk) * H + n];
    }
    Bt3[(size_t)l * H * KTOT + (size_t)n * KTOT + krow] = __float2bfloat16(v);
}

// ===================== edge-feature path =====================
__global__ __launch_bounds__(256) void edge_table_kernel(
    const float* __restrict__ emb, const float* __restrict__ mlp_w,
    const float* __restrict__ mlp_b, float* __restrict__ ctab, float* __restrict__ wlast) {
    int r = blockIdx.x, j = threadIdx.x;
    float acc = mlp_b[j];
    #pragma unroll
    for (int k = 0; k < EDIM; ++k) acc += emb[r * EDIM + k] * mlp_w[k * H + j];
    ctab[r * H + j] = acc;
    if (r == 0) wlast[j] = mlp_w[EDIM * H + j];
}

__global__ __launch_bounds__(256) void enh_bucket_kernel(
    const int* __restrict__ offs, const float* __restrict__ sew,
    const float* __restrict__ ctab, const float* __restrict__ wlast,
    bf16* __restrict__ enh) {
    __shared__ float ct[R * H];
    __shared__ float wl[H];
    for (int i = threadIdx.x; i < R * H; i += 256) ct[i] = ctab[i];
    for (int i = threadIdx.x; i < H; i += 256) wl[i] = wlast[i];
    __syncthreads();
    int w = threadIdx.x >> 6, lane = threadIdx.x & 63;
    int d = blockIdx.x * 4 + w;
    float acc[4] = {0.f, 0.f, 0.f, 0.f};
    int deg = offs[d * R + R] - offs[d * R];
    for (int r = 0; r < R; ++r) {
        int a = offs[d * R + r], b = offs[d * R + r + 1];
        for (int j = a; j < b; ++j) {
            float wt = sew[j];
            #pragma unroll
            for (int i = 0; i < 4; ++i) {
                int c = lane * 4 + i;
                acc[i] += fmaxf(ct[r * H + c] + wt * wl[c], 0.0f);
            }
        }
    }
    float inv = 1.0f / fmaxf((float)deg, 1.0f);
    unsigned short o[4];
    #pragma unroll
    for (int i = 0; i < 4; ++i) { bf16 hv = __float2bfloat16(acc[i] * inv); o[i] = *(unsigned short*)&hv; }
    *(ushort4*)(enh + (size_t)d * H + lane * 4) = *(ushort4*)o;
}

// ===================== bucket sums: pre[d][r*256+c] = cinv * sum hb[src][c] =====================
// block = one dst; wave w handles relations 2w, 2w+1
__global__ __launch_bounds__(256) void bucket_msg_kernel(
    const int* __restrict__ offs, const int* __restrict__ ssrc,
    const bf16* __restrict__ hbR, const float* __restrict__ cinv,
    bf16* __restrict__ pre, int c0) {
    int w = threadIdx.x >> 6, lane = threadIdx.x & 63;
    int d = c0 + blockIdx.x;
    size_t prow = (size_t)blockIdx.x * KPRE;
    #pragma unroll
    for (int rr = 0; rr < 2; ++rr) {
        int r = w * 2 + rr;
        float acc[4] = {0.f, 0.f, 0.f, 0.f};
        int a = offs[d * R + r], b = offs[d * R + r + 1];
        for (int j = a; j < b; ++j) {
            int s = ssrc[j];
            ushort4 u = *(const ushort4*)(hbR + (size_t)s * H + lane * 4);
            acc[0] += us2f(u.x); acc[1] += us2f(u.y); acc[2] += us2f(u.z); acc[3] += us2f(u.w);
        }
        float sc = cinv[d * R + r];
        unsigned short o[4];
        #pragma unroll
        for (int i = 0; i < 4; ++i) { bf16 hv = __float2bfloat16(acc[i] * sc); o[i] = *(unsigned short*)&hv; }
        *(ushort4*)(pre + prow + r * H + lane * 4) = *(ushort4*)o;
    }
}

// ===================== layer GEMM + fused LN/ReLU/residual =====================
// agg_row = [pre | hbR_row] (K=2304) @ Bt^T, then h += relu(LN(agg+bias+0.1*enh)), refresh hbW
__global__ __launch_bounds__(256) void gemm_ln_kernel(
    const bf16* __restrict__ pre, const bf16* __restrict__ hbR,
    const bf16* __restrict__ Bt, const bf16* __restrict__ enh,
    const float* __restrict__ bias, const float* __restrict__ gamma, const float* __restrict__ beta,
    float* __restrict__ h, bf16* __restrict__ hbW, int c0) {
    __shared__ bf16 bts[256 * 40];
    int t = threadIdx.x, w = t >> 6, lane = t & 63;
    int quad = lane >> 4, m = lane & 15;
    int rowbase = blockIdx.x * 64 + w * 16;
    f32x4 acc[16];
    #pragma unroll
    for (int c = 0; c < 16; ++c) { acc[c][0] = 0.f; acc[c][1] = 0.f; acc[c][2] = 0.f; acc[c][3] = 0.f; }
    int rowA = rowbase + m;
    int rA = (rowA < NC) ? rowA : (NC - 1);
    const bf16* Apre = pre + (size_t)rA * KPRE;
    const bf16* Ahb  = hbR + (size_t)(c0 + rA) * H;

    for (int kc = 0; kc < KTOT / 32; ++kc) {
        int k0 = kc * 32;
        {
            const bf16* g = Bt + (size_t)t * KTOT + k0;
            bf16* l = bts + t * 40;
            *(bf16x8*)(l + 0)  = *(const bf16x8*)(g + 0);
            *(bf16x8*)(l + 8)  = *(const bf16x8*)(g + 8);
            *(bf16x8*)(l + 16) = *(const bf16x8*)(g + 16);
            *(bf16x8*)(l + 24) = *(const bf16x8*)(g + 24);
        }
        bf16x8 a;
        if (k0 < KPRE) a = *(const bf16x8*)(Apre + k0 + quad * 8);
        else           a = *(const bf16x8*)(Ahb + (k0 - KPRE) + quad * 8);
        __syncthreads();
        #pragma unroll
        for (int c = 0; c < 16; ++c) {
            bf16x8 b = *(const bf16x8*)(bts + (c * 16 + m) * 40 + quad * 8);
            acc[c] = __builtin_amdgcn_mfma_f32_16x16x32_bf16(a, b, acc[c], 0, 0, 0);
        }
        __syncthreads();
    }

    // epilogue: v = acc + bias + 0.1*enh ; LN over 256 cols (16 lanes x 16 c-groups) ; relu ; residual
    float bv[16], gv[16], tv[16];
    #pragma unroll
    for (int c = 0; c < 16; ++c) {
        int col = c * 16 + m;
        bv[c] = bias[col]; gv[c] = gamma[col]; tv[c] = beta[col];
    }
    float s[4] = {0.f,0.f,0.f,0.f}, s2[4] = {0.f,0.f,0.f,0.f};
    #pragma unroll
    for (int c = 0; c < 16; ++c) {
        #pragma unroll
        for (int i = 0; i < 4; ++i) {
            int row = rowbase + quad * 4 + i;
            int rr = (row < NC) ? row : (NC - 1);
            float e = us2f(*(const unsigned short*)(enh + (size_t)(c0 + rr) * H + c * 16 + m));
            float val = acc[c][i] + bv[c] + 0.1f * e;
            acc[c][i] = val;
            s[i] += val; s2[i] += val * val;
        }
    }
    #pragma unroll
    for (int msk = 1; msk < 16; msk <<= 1) {
        #pragma unroll
        for (int i = 0; i < 4; ++i) { s[i] += __shfl_xor(s[i], msk); s2[i] += __shfl_xor(s2[i], msk); }
    }
    float mu[4], rstd[4];
    #pragma unroll
    for (int i = 0; i < 4; ++i) {
        mu[i] = s[i] * (1.0f / H);
        float var = s2[i] * (1.0f / H) - mu[i] * mu[i];
        rstd[i] = rsqrtf(var + LN_EPS);
    }
    #pragma unroll
    for (int c = 0; c < 16; ++c) {
        #pragma unroll
        for (int i = 0; i < 4; ++i) {
            int row = rowbase + quad * 4 + i;
            if (row < NC) {
                size_t idx = (size_t)(c0 + row) * H + c * 16 + m;
                float y = (acc[c][i] - mu[i]) * rstd[i] * gv[c] + tv[c];
                float hn = h[idx] + fmaxf(y, 0.0f);
                h[idx] = hn;
                hbW[idx] = __float2bfloat16(hn);
            }
        }
    }
}

// ===================== input projection GEMM + fused LN/ReLU =====================
__global__ __launch_bounds__(256) void proj_gemm_kernel(
    const bf16* __restrict__ xevb, const bf16* __restrict__ xiob,
    const bf16* __restrict__ wevT, const bf16* __restrict__ wioT,
    const float* __restrict__ bev, const float* __restrict__ gev, const float* __restrict__ betev,
    const float* __restrict__ bio, const float* __restrict__ gio, const float* __restrict__ betio,
    float* __restrict__ h, bf16* __restrict__ hbW) {
    __shared__ bf16 bts[256 * 40];
    int t = threadIdx.x, w = t >> 6, lane = t & 63;
    int quad = lane >> 4, m = lane & 15;
    int blk = blockIdx.x;
    const bf16 *X, *WT; const float *bb, *gg, *be;
    int K, node0, x0, nvalid;
    if (blk < NBLK_EV) {
        X = xevb; WT = wevT; K = D_EV; node0 = blk * 64; x0 = node0;
        bb = bev; gg = gev; be = betev;
        nvalid = (N_EVENT - node0 < 64) ? (N_EVENT - node0) : 64;
    } else {
        int b2 = blk - NBLK_EV;
        X = xiob; WT = wioT; K = D_IO; node0 = N_EVENT + b2 * 64; x0 = b2 * 64;
        bb = bio; gg = gio; be = betio;
        nvalid = 64;
    }
    int rowbase = w * 16;
    f32x4 acc[16];
    #pragma unroll
    for (int c = 0; c < 16; ++c) { acc[c][0] = 0.f; acc[c][1] = 0.f; acc[c][2] = 0.f; acc[c][3] = 0.f; }
    int rowA = rowbase + m;
    int rA = (rowA < nvalid) ? rowA : (nvalid - 1);
    const bf16* Ax = X + (size_t)(x0 + rA) * K;

    for (int kc = 0; kc < K / 32; ++kc) {
        int k0 = kc * 32;
        {
            const bf16* g = WT + (size_t)t * K + k0;
            bf16* l = bts + t * 40;
            *(bf16x8*)(l + 0)  = *(const bf16x8*)(g + 0);
            *(bf16x8*)(l + 8)  = *(const bf16x8*)(g + 8);
            *(bf16x8*)(l + 16) = *(const bf16x8*)(g + 16);
            *(bf16x8*)(l + 24) = *(const bf16x8*)(g + 24);
        }
        bf16x8 a = *(const bf16x8*)(Ax + k0 + quad * 8);
        __syncthreads();
        #pragma unroll
        for (int c = 0; c < 16; ++c) {
            bf16x8 b = *(const bf16x8*)(bts + (c * 16 + m) * 40 + quad * 8);
            acc[c] = __builtin_amdgcn_mfma_f32_16x16x32_bf16(a, b, acc[c], 0, 0, 0);
        }
        __syncthreads();
    }

    float bv[16], gv[16], tv[16];
    #pragma unroll
    for (int c = 0; c < 16; ++c) {
        int col = c * 16 + m;
        bv[c] = bb[col]; gv[c] = gg[col]; tv[c] = be[col];
    }
    float s[4] = {0.f,0.f,0.f,0.f}, s2[4] = {0.f,0.f,0.f,0.f};
    #pragma unroll
    for (int c = 0; c < 16; ++c) {
        #pragma unroll
        for (int i = 0; i < 4; ++i) {
            float val = acc[c][i] + bv[c];
            acc[c][i] = val;
            s[i] += val; s2[i] += val * val;
        }
    }
    #pragma unroll
    for (int msk = 1; msk < 16; msk <<= 1) {
        #pragma unroll
        for (int i = 0; i < 4; ++i) { s[i] += __shfl_xor(s[i], msk); s2[i] += __shfl_xor(s2[i], msk); }
    }
    float mu[4], rstd[4];
    #pragma unroll
    for (int i = 0; i < 4; ++i) {
        mu[i] = s[i] * (1.0f / H);
        float var = s2[i] * (1.0f / H) - mu[i] * mu[i];
        rstd[i] = rsqrtf(var + LN_EPS);
    }
    #pragma unroll
    for (int c = 0; c < 16; ++c) {
        #pragma unroll
        for (int i = 0; i < 4; ++i) {
            int row = rowbase + quad * 4 + i;
            if (row < nvalid) {
                size_t idx = (size_t)(node0 + row) * H + c * 16 + m;
                float y = (acc[c][i] - mu[i]) * rstd[i] * gv[c] + tv[c];
                float hn = fmaxf(y, 0.0f);
                h[idx] = hn;
                hbW[idx] = __float2bfloat16(hn);
            }
        }
    }
}

extern "C" void kernel_launch(void* const* d_in, const int* in_sizes, int n_in,
                              void* d_out, int out_size, void* d_ws, size_t ws_size,
                              hipStream_t stream) {
    const float* xev   = (const float*)d_in[0];
    const float* xio   = (const float*)d_in[1];
    const int*   ei    = (const int*)d_in[2];
    const int*   et    = (const int*)d_in[3];
    const float* ew    = (const float*)d_in[4];
    const float* wev   = (const float*)d_in[5];
    const float* bev   = (const float*)d_in[6];
    const float* gev   = (const float*)d_in[7];
    const float* betev = (const float*)d_in[8];
    const float* wio   = (const float*)d_in[9];
    const float* bio   = (const float*)d_in[10];
    const float* gio   = (const float*)d_in[11];
    const float* betio = (const float*)d_in[12];
    const float* emb   = (const float*)d_in[13];
    const float* mlp_w = (const float*)d_in[14];
    const float* mlp_b = (const float*)d_in[15];
    const float* bases = (const float*)d_in[16];
    const float* comp  = (const float*)d_in[17];
    const float* root  = (const float*)d_in[18];
    const float* bias  = (const float*)d_in[19];
    const float* gamma = (const float*)d_in[20];
    const float* beta  = (const float*)d_in[21];

    char* base = (char*)d_ws;
    size_t o = 0;
    auto alloc = [&](size_t bytes) { char* p = base + o; o = (o + bytes + 255) & ~(size_t)255; return p; };
    float* h    = (float*)alloc((size_t)N_NODES * H * 4);          // 51.2 MB
    bf16*  hbA  = (bf16*) alloc((size_t)N_NODES * H * 2);          // 25.6 MB
    bf16*  hbB  = (bf16*) alloc((size_t)N_NODES * H * 2);          // 25.6 MB
    bf16*  enh  = (bf16*) alloc((size_t)N_NODES * H * 2);          // 25.6 MB
    char*  un   = alloc((size_t)NC * KPRE * 2);                    // 51.2 MB union
    bf16*  pre  = (bf16*)un;                                       //   pre (layers)
    bf16*  xevb = (bf16*)un;                                       //   x bf16 (proj only)
    bf16*  xiob = (bf16*)(un + (size_t)N_EVENT * D_EV * 2);
    bf16*  wevT = (bf16*) alloc((size_t)H * D_EV * 2);
    bf16*  wioT = (bf16*) alloc((size_t)H * D_IO * 2);
    bf16*  Bt3  = (bf16*) alloc((size_t)NLAYERS * H * KTOT * 2);   // 3.5 MB
    float* ctab = (float*)alloc(R * H * 4);
    float* wlast= (float*)alloc(H * 4);
    float* cinv = (float*)alloc((size_t)NKEY * 4);
    int*   bsum = (int*)  alloc(256 * 4);
    int*   cnt  = (int*)  alloc((size_t)NKEY * 4);
    int*   offs = (int*)  alloc((size_t)(NKEY + 4) * 4);
    int*   ssrc = (int*)  alloc((size_t)E_EDGES * 4);
    float* sew  = (float*)alloc((size_t)E_EDGES * 4);
    // total ~195 MB

    hipMemsetAsync(cnt, 0, (size_t)NKEY * sizeof(int), stream);

    // edge presort
    hist_kernel<<<(E_EDGES + 255) / 256, 256, 0, stream>>>(ei, et, cnt);
    scan1_kernel<<<NCHUNK, 256, 0, stream>>>(cnt, offs, bsum);
    scan2_kernel<<<1, 256, 0, stream>>>(bsum);
    scan3_kernel<<<(NKEY + 255) / 256, 256, 0, stream>>>(offs, bsum);
    cinv_kernel<<<(NKEY + 255) / 256, 256, 0, stream>>>(cnt, cinv);
    sort_kernel<<<(E_EDGES + 255) / 256, 256, 0, stream>>>(ei, et, ew, offs, cnt, ssrc, sew);

    // dtype prep
    cvt_x_kernel<<<12500, 256, 0, stream>>>(xev, xio, xevb, xiob);
    cvt_w_kernel<<<H, 256, 0, stream>>>(wev, wio, wevT, wioT);
    build_Bt_kernel<<<NLAYERS * KTOT, 256, 0, stream>>>(bases, comp, root, Bt3);

    // node features + edge-feature means
    proj_gemm_kernel<<<NBLK_EV + NBLK_IO, 256, 0, stream>>>(
        xevb, xiob, wevT, wioT, bev, gev, betev, bio, gio, betio, h, hbA);
    edge_table_kernel<<<R, 256, 0, stream>>>(emb, mlp_w, mlp_b, ctab, wlast);
    enh_bucket_kernel<<<N_NODES / 4, 256, 0, stream>>>(offs, sew, ctab, wlast, enh);

    for (int l = 0; l < NLAYERS; ++l) {
        bf16* hbR = (l & 1) ? hbB : hbA;
        bf16* hbW = (l & 1) ? hbA : hbB;
        const bf16* Bt = Bt3 + (size_t)l * H * KTOT;
        for (int c = 0; c < NCHUNKS; ++c) {
            int c0 = c * NC;
            bucket_msg_kernel<<<NC, 256, 0, stream>>>(offs, ssrc, hbR, cinv, pre, c0);
            gemm_ln_kernel<<<(NC + 63) / 64, 256, 0, stream>>>(
                pre, hbR, Bt, enh, bias + l * H, gamma + l * H, beta + l * H, h, hbW, c0);
        }
    }

    hipMemcpyAsync(d_out, h, (size_t)N_EVENT * H * sizeof(float), hipMemcpyDeviceToDevice, stream);
}